// Round 2
// baseline (1685.123 us; speedup 1.0000x reference)
//
#include <hip/hip_runtime.h>

// CRF Viterbi forward decode — R1: LDS-free, barrier-free.
// potentials: [1024, 512, 48] f32, transition: [48, 48] f32.
// out = backpointers [1024, 511, 48] (as float values) ++ scores [1024, 48] f32.
//
// Layout: 1 block = 1 wave, 48 active lanes = 1 batch; lane = destination tag j.
// trans column j in 48 VGPRs. State broadcast via v_readlane (48 SGPRs) —
// no LDS, no __syncthreads on the 511-step serial path (R0 post-mortem:
// LDS+barrier latency was ~2700 of 3170 cyc/step at 1 wave/SIMD).
// Argmax: 24 independent pair chains + strict-'>' tree merge over ascending
// contiguous blocks = first-occurrence tie-breaking, bit-exact vs jnp ref.

constexpr int B_ = 1024;
constexpr int T_ = 512;
constexpr int K_ = 48;

__global__ __launch_bounds__(64) void crf_viterbi_kernel(
    const float* __restrict__ pot,
    const float* __restrict__ trans,
    float* __restrict__ out)
{
    const int b = blockIdx.x;
    const int j = threadIdx.x;  // 0..47

    // Transition column j -> registers (reused 511 times).
    float tcol[K_];
    #pragma unroll
    for (int i = 0; i < K_; ++i) tcol[i] = trans[i * K_ + j];

    const float* pp = pot + (size_t)b * T_ * K_ + j;
    float* bpout    = out + (size_t)b * (T_ - 1) * K_ + j;
    float* scout    = out + (size_t)B_ * (T_ - 1) * K_ + (size_t)b * K_ + j;

    // t = 0 state (lane j holds state[j]).
    float myst = pp[0];

    // Prefetch potentials for t = 1..4.
    float pbuf[4];
    #pragma unroll
    for (int u = 0; u < 4; ++u) pbuf[u] = pp[(1 + u) * K_];

    for (int t0 = 1; t0 < T_; t0 += 4) {
        float pc[4];
        #pragma unroll
        for (int u = 0; u < 4; ++u) pc[u] = pbuf[u];

        // Prefetch next chunk (clamped; duplicate loads harmless).
        #pragma unroll
        for (int u = 0; u < 4; ++u) {
            int tn = t0 + 4 + u;
            if (tn > T_ - 1) tn = T_ - 1;
            pbuf[u] = pp[tn * K_];
        }

        #pragma unroll
        for (int u = 0; u < 4; ++u) {
            const int t = t0 + u;
            if (t < T_) {  // wave-uniform guard; only fails in last chunk
                // Broadcast all 48 state values to SGPRs (exec-independent,
                // no memory pipe, no barrier).
                float s[K_];
                #pragma unroll
                for (int i = 0; i < K_; ++i)
                    s[i] = __int_as_float(
                        __builtin_amdgcn_readlane(__float_as_int(myst), i));

                // Pair stage: 24 independent chains, i0 < i1, right wins only
                // on strict '>' -> first-occurrence ties.
                float m[24];
                int   x[24];
                #pragma unroll
                for (int p = 0; p < 24; ++p) {
                    const int i0 = 2 * p, i1 = 2 * p + 1;
                    float c0 = s[i0] + tcol[i0];
                    float c1 = s[i1] + tcol[i1];
                    bool g = c1 > c0;
                    m[p] = g ? c1 : c0;
                    x[p] = g ? i1 : i0;
                }
                // Tree merge: adjacent blocks (left = lower indices), right
                // wins only on strict '>'.
                #pragma unroll
                for (int w = 24; w >= 6; w /= 2) {
                    #pragma unroll
                    for (int p = 0; p < w / 2; ++p) {
                        bool g = m[2 * p + 1] > m[2 * p];
                        m[p] = g ? m[2 * p + 1] : m[2 * p];
                        x[p] = g ? x[2 * p + 1] : x[2 * p];
                    }
                }
                // 3 blocks left: (0-15), (16-31), (32-47).
                {
                    bool g = m[1] > m[0];
                    float mm = g ? m[1] : m[0];
                    int   xx = g ? x[1] : x[0];
                    bool g2 = m[2] > mm;
                    mm = g2 ? m[2] : mm;
                    xx = g2 ? x[2] : xx;

                    myst = pc[u] + mm;
                    bpout[(size_t)(t - 1) * K_] = (float)xx;
                }
            }
        }
    }

    // Final Viterbi scores.
    *scout = myst;
}

extern "C" void kernel_launch(void* const* d_in, const int* in_sizes, int n_in,
                              void* d_out, int out_size, void* d_ws, size_t ws_size,
                              hipStream_t stream) {
    const float* pot   = (const float*)d_in[0];
    const float* trans = (const float*)d_in[1];
    float* out         = (float*)d_out;
    crf_viterbi_kernel<<<dim3(B_), dim3(K_), 0, stream>>>(pot, trans, out);
}